// Round 7
// baseline (130.612 us; speedup 1.0000x reference)
//
#include <hip/hip_runtime.h>

#define EPS 1e-5f

typedef unsigned short u16;
typedef __attribute__((ext_vector_type(8))) __bf16 bf16x8;
typedef __attribute__((ext_vector_type(4))) float f32x4;
typedef __attribute__((ext_vector_type(8))) unsigned short ushort8;

__device__ inline float bf2f(u16 h) {
  union { unsigned u; float f; } x; x.u = ((unsigned)h) << 16; return x.f;
}
__device__ inline u16 f2bf(float f) {
  union { float f; unsigned u; } x; x.f = f;
  unsigned r = x.u + 0x7fffu + ((x.u >> 16) & 1u);
  return (u16)(r >> 16);
}
__device__ inline float sigmoidf(float x) { return 1.0f / (1.0f + __expf(-x)); }

// ---------------- cast: 4 equal-size f32 -> bf16(u16) arrays ----------------
__global__ __launch_bounds__(256) void cast4_f32_bf16(
    const float* __restrict__ s0, const float* __restrict__ s1,
    const float* __restrict__ s2, const float* __restrict__ s3,
    u16* __restrict__ d0, u16* __restrict__ d1,
    u16* __restrict__ d2, u16* __restrict__ d3, int n)
{
  const float* s = (blockIdx.y == 0) ? s0 : (blockIdx.y == 1) ? s1 : (blockIdx.y == 2) ? s2 : s3;
  u16*         d = (blockIdx.y == 0) ? d0 : (blockIdx.y == 1) ? d1 : (blockIdx.y == 2) ? d2 : d3;
  int i = (blockIdx.x * 256 + threadIdx.x) * 8;
  if (i >= n) return;
  float4 a = *(const float4*)(s + i);
  float4 b = *(const float4*)(s + i + 4);
  ushort8 o;
  o[0] = f2bf(a.x); o[1] = f2bf(a.y); o[2] = f2bf(a.z); o[3] = f2bf(a.w);
  o[4] = f2bf(b.x); o[5] = f2bf(b.y); o[6] = f2bf(b.z); o[7] = f2bf(b.w);
  *(ushort8*)(d + i) = o;
}

// ---------------- GEMM: C[m][n] = sum_k A[m][k] * W[n][k] -------------------
// 256x128 tile, BK=32, 256 threads (4 waves, 2Mx2N), 48 KiB LDS double-buffer
// -> 2 INDEPENDENT blocks/CU (separate barrier groups: one block's stalls are
// covered by the other's MFMA -- m114 TLP mechanism; R4's attempt failed only
// because launch_bounds forced VGPR=64 -> acc spill; here cap is 256).
// BK=32 natural layout is bank-conflict-free for b128 reads: lane bank-start
// = 16*(row&1) + 4*k8 -> all 32 banks hit exactly 8x. No swizzle needed.
// T4: counted vmcnt(6), 1 tile prefetch in flight, last tile peeled.
// T1: bijective XCD swizzle (1024 % 8 == 0). gload_lds offset=0 always (R6
// lesson: the offset-imm corrupts LDS-DMA addressing; advance pointers).
#define MFMA_ __builtin_amdgcn_mfma_f32_16x16x32_bf16
#define ASG __attribute__((address_space(1)))
#define ASL __attribute__((address_space(3)))

#define GLL(p, lds) __builtin_amdgcn_global_load_lds( \
    (const ASG void*)(p), (ASL void*)(lds), 16, 0, 0);

// stage one K-tile (A 256x32 + B 128x32) into buffer nx at k-offset kt:
// 6 x 16B chunks per thread, linear LDS, coalesced 1-KiB-per-wave global reads.
#define STAGE(nx, kt) { \
  GLL(gA0 + (kt), &sA[nx][(      tid) * 8]) \
  GLL(gA1 + (kt), &sA[nx][(256 + tid) * 8]) \
  GLL(gA2 + (kt), &sA[nx][(512 + tid) * 8]) \
  GLL(gA3 + (kt), &sA[nx][(768 + tid) * 8]) \
  GLL(gB0 + (kt), &sB[nx][(      tid) * 8]) \
  GLL(gB1 + (kt), &sB[nx][(256 + tid) * 8]) }

#define LDA(mi) (*(const bf16x8*)&sa[(arow + (mi) * 16) * 32 + k8e])
#define LDB(ni) (*(const bf16x8*)&sb[(brow + (ni) * 16) * 32 + k8e])

// one K-tile: 12 ds_read_b128 then 32 MFMA (compiler inserts fine lgkm counts)
#define CTILE { \
  bf16x8 qf0 = LDB(0), qf1 = LDB(1), qf2 = LDB(2), qf3 = LDB(3); \
  bf16x8 af[8]; \
  _Pragma("unroll") for (int mi = 0; mi < 8; ++mi) af[mi] = LDA(mi); \
  __builtin_amdgcn_s_setprio(1); \
  _Pragma("unroll") for (int mi = 0; mi < 8; ++mi) { \
    acc[mi][0] = MFMA_(af[mi], qf0, acc[mi][0], 0, 0, 0); \
    acc[mi][1] = MFMA_(af[mi], qf1, acc[mi][1], 0, 0, 0); \
    acc[mi][2] = MFMA_(af[mi], qf2, acc[mi][2], 0, 0, 0); \
    acc[mi][3] = MFMA_(af[mi], qf3, acc[mi][3], 0, 0, 0); \
  } \
  __builtin_amdgcn_s_setprio(0); }

__global__ __launch_bounds__(256, 2) void gemm256x128_dual(
    const u16* __restrict__ A0, const u16* __restrict__ W0, u16* __restrict__ C0,
    const u16* __restrict__ A1, const u16* __restrict__ W1, u16* __restrict__ C1)
{
  constexpr int K = 1024, N = 4096, NT = 32;  // K-tiles of 32

  __shared__ __attribute__((aligned(16))) u16 sA[2][256 * 32];  // 2 x 16 KiB
  __shared__ __attribute__((aligned(16))) u16 sB[2][128 * 32];  // 2 x  8 KiB

  // T1: bijective XCD swizzle (1024 blocks % 8 XCDs == 0)
  const int b0  = blockIdx.x;
  const int bid = (b0 & 7) * 128 + (b0 >> 3);

  const u16* A  = (bid < 512) ? A0 : A1;
  const u16* Wm = (bid < 512) ? W0 : W1;
  u16*       C  = (bid < 512) ? C0 : C1;
  const int b2 = bid & 511;
  const int bm = (b2 >> 5) << 8;   // 16 m-tiles of 256
  const int bn = (b2 & 31) << 7;   // 32 n-tiles of 128

  const int tid = threadIdx.x;
  const int l  = tid & 63;
  const int w  = tid >> 6;   // wave 0..3
  const int wr = w >> 1;     // 0..1 -> M offset wr*128
  const int wc = w & 1;      // 0..1 -> N offset wc*64

  // staging source: chunk c = i*256 + tid -> LDS byte c*16 -> row c>>2,
  // slot tid&3. Global: row (i*64 + tid>>2), col (tid&3)*8. Linear both sides.
  const int r0 = tid >> 2;
  const int sc = (tid & 3) * 8;
  const u16* gA0 = A  + (size_t)(bm + r0) * K + sc;
  const u16* gA1 = gA0 + (size_t)64  * K;
  const u16* gA2 = gA0 + (size_t)128 * K;
  const u16* gA3 = gA0 + (size_t)192 * K;
  const u16* gB0 = Wm + (size_t)(bn + r0) * K + sc;
  const u16* gB1 = gB0 + (size_t)64 * K;

  // fragment reads: row = base + mi*16 + (l&15), 16B slot k8 = l>>4
  const int arow = wr * 128 + (l & 15);
  const int brow = wc * 64 + (l & 15);
  const int k8e  = (l >> 4) * 8;

  f32x4 acc[8][4];
#pragma unroll
  for (int i = 0; i < 8; ++i)
#pragma unroll
    for (int j = 0; j < 4; ++j) acc[i][j] = (f32x4){0.f, 0.f, 0.f, 0.f};

  // prologue: stage K-tile 0 into buffer 0 (6 loads in flight, NO drain)
  STAGE(0, 0)

  for (int t = 0; t < NT - 1; ++t) {
    const int cur = t & 1, nxt = cur ^ 1;
    STAGE(nxt, (t + 1) * 32)                          // outstanding: 6 + 6
    asm volatile("s_waitcnt vmcnt(6)" ::: "memory");  // tile t landed
    __builtin_amdgcn_s_barrier();
    const u16* sa = sA[cur];
    const u16* sb = sB[cur];
    CTILE
    // trailing barrier: all waves' ds_reads of buf[cur] completed (lgkm wait
    // precedes MFMA) before any wave stages tile t+2 into buf[cur].
    __builtin_amdgcn_s_barrier();
  }

  {  // peeled last tile (t = NT-1, buf 1)
    asm volatile("s_waitcnt vmcnt(0)" ::: "memory");
    __builtin_amdgcn_s_barrier();
    const u16* sa = sA[1];
    const u16* sb = sB[1];
    CTILE
  }

  // C write: col = lane&15, row = (lane>>4)*4 + reg  (m89/m91-verified layout)
  const int ccol = bn + wc * 64 + (l & 15);
  const int crow = bm + wr * 128 + (l >> 4) * 4;
#pragma unroll
  for (int mi = 0; mi < 8; ++mi) {
#pragma unroll
    for (int ni = 0; ni < 4; ++ni) {
      int col = ccol + ni * 16;
#pragma unroll
      for (int r = 0; r < 4; ++r) {
        int row = crow + mi * 16 + r;
        C[(size_t)row * N + col] = f2bf(acc[mi][ni][r]);
      }
    }
  }
}

// ---------------- fused LN(ig) + LN(hg) + gates + cell-LN + outputs ----------
__global__ __launch_bounds__(256) void lstm_epilogue(
    const u16* __restrict__ ig, const u16* __restrict__ hg,
    const float* __restrict__ cx,
    const float* __restrict__ gi, const float* __restrict__ bi,
    const float* __restrict__ gh, const float* __restrict__ bh,
    const float* __restrict__ gc, const float* __restrict__ bc,
    float* __restrict__ out)
{
  const int b = blockIdx.x;
  const int t = threadIdx.x;
  const u16* igr = ig + (size_t)b * 4096;
  const u16* hgr = hg + (size_t)b * 4096;

  __shared__ float redbuf[16];

  float iv[16], hv[16];
  float s_i = 0.f, q_i = 0.f, s_h = 0.f, q_h = 0.f;
#pragma unroll
  for (int i = 0; i < 16; ++i) {
    float a = bf2f(igr[t + 256 * i]);
    float c = bf2f(hgr[t + 256 * i]);
    iv[i] = a; hv[i] = c;
    s_i += a; q_i += a * a; s_h += c; q_h += c * c;
  }
#pragma unroll
  for (int off = 32; off > 0; off >>= 1) {
    s_i += __shfl_xor(s_i, off);
    q_i += __shfl_xor(q_i, off);
    s_h += __shfl_xor(s_h, off);
    q_h += __shfl_xor(q_h, off);
  }
  {
    int wv = t >> 6;
    if ((t & 63) == 0) {
      redbuf[wv] = s_i; redbuf[wv + 4] = q_i;
      redbuf[wv + 8] = s_h; redbuf[wv + 12] = q_h;
    }
    __syncthreads();
    s_i = redbuf[0] + redbuf[1] + redbuf[2] + redbuf[3];
    q_i = redbuf[4] + redbuf[5] + redbuf[6] + redbuf[7];
    s_h = redbuf[8] + redbuf[9] + redbuf[10] + redbuf[11];
    q_h = redbuf[12] + redbuf[13] + redbuf[14] + redbuf[15];
    __syncthreads();
  }
  const float inv4096 = 1.0f / 4096.0f;
  float mu_i = s_i * inv4096;
  float rs_i = rsqrtf(q_i * inv4096 - mu_i * mu_i + EPS);
  float mu_h = s_h * inv4096;
  float rs_h = rsqrtf(q_h * inv4096 - mu_h * mu_h + EPS);

  float c_pre[4], og[4];
  float s_c = 0.f, q_c = 0.f;
#pragma unroll
  for (int i = 0; i < 4; ++i) {
    int h = t + 256 * i;
    float g_in = ((iv[i]      - mu_i) * rs_i * gi[h]        + bi[h]) +
                 ((hv[i]      - mu_h) * rs_h * gh[h]        + bh[h]);
    float g_fg = ((iv[i + 4]  - mu_i) * rs_i * gi[h + 1024] + bi[h + 1024]) +
                 ((hv[i + 4]  - mu_h) * rs_h * gh[h + 1024] + bh[h + 1024]);
    float g_cl = ((iv[i + 8]  - mu_i) * rs_i * gi[h + 2048] + bi[h + 2048]) +
                 ((hv[i + 8]  - mu_h) * rs_h * gh[h + 2048] + bh[h + 2048]);
    float g_og = ((iv[i + 12] - mu_i) * rs_i * gi[h + 3072] + bi[h + 3072]) +
                 ((hv[i + 12] - mu_h) * rs_h * gh[h + 3072] + bh[h + 3072]);
    float in_s = sigmoidf(g_in);
    float fg_s = sigmoidf(g_fg);
    float cl_t = tanhf(g_cl);
    og[i] = sigmoidf(g_og);
    c_pre[i] = fg_s * cx[(size_t)b * 1024 + h] + in_s * cl_t;
    s_c += c_pre[i]; q_c += c_pre[i] * c_pre[i];
  }
#pragma unroll
  for (int off = 32; off > 0; off >>= 1) {
    s_c += __shfl_xor(s_c, off);
    q_c += __shfl_xor(q_c, off);
  }
  {
    int wv = t >> 6;
    if ((t & 63) == 0) { redbuf[wv] = s_c; redbuf[wv + 4] = q_c; }
    __syncthreads();
    s_c = redbuf[0] + redbuf[1] + redbuf[2] + redbuf[3];
    q_c = redbuf[4] + redbuf[5] + redbuf[6] + redbuf[7];
  }
  const float inv1024 = 1.0f / 1024.0f;
  float mu_c = s_c * inv1024;
  float rs_c = rsqrtf(q_c * inv1024 - mu_c * mu_c + EPS);

  const size_t BH = (size_t)4096 * 1024;
#pragma unroll
  for (int i = 0; i < 4; ++i) {
    int h = t + 256 * i;
    float cy = (c_pre[i] - mu_c) * rs_c * gc[h] + bc[h];
    float hy = og[i] * tanhf(cy);
    size_t o = (size_t)b * 1024 + h;
    out[o] = hy;
    out[BH + o] = hy;
    out[2 * BH + o] = cy;
  }
}

extern "C" void kernel_launch(void* const* d_in, const int* in_sizes, int n_in,
                              void* d_out, int out_size, void* d_ws, size_t ws_size,
                              hipStream_t stream) {
  const float* input = (const float*)d_in[0];
  const float* hx    = (const float*)d_in[1];
  const float* cx    = (const float*)d_in[2];
  const float* wih   = (const float*)d_in[3];
  const float* whh   = (const float*)d_in[4];
  const float* gi    = (const float*)d_in[5];
  const float* bi    = (const float*)d_in[6];
  const float* gh    = (const float*)d_in[7];
  const float* bh    = (const float*)d_in[8];
  const float* gc    = (const float*)d_in[9];
  const float* bc    = (const float*)d_in[10];
  float* out = (float*)d_out;

  char* wsp = (char*)d_ws;
  u16* a_bf  = (u16*)(wsp);
  u16* h_bf  = (u16*)(wsp + ((size_t)8  << 20));
  u16* wi_bf = (u16*)(wsp + ((size_t)16 << 20));
  u16* wh_bf = (u16*)(wsp + ((size_t)24 << 20));
  u16* ig_bf = (u16*)(wsp + ((size_t)32 << 20));
  u16* hg_bf = (u16*)(wsp + ((size_t)64 << 20));

  const int nper = 4096 * 1024;
  dim3 cgrid(nper / 8 / 256, 4);
  cast4_f32_bf16<<<cgrid, 256, 0, stream>>>(input, hx, wih, whh,
                                            a_bf, h_bf, wi_bf, wh_bf, nper);

  gemm256x128_dual<<<1024, 256, 0, stream>>>(a_bf, wi_bf, ig_bf,
                                             h_bf, wh_bf, hg_bf);

  lstm_epilogue<<<4096, 256, 0, stream>>>(ig_bf, hg_bf, cx,
                                          gi, bi, gh, bh, gc, bc, out);
}

// Round 8
// 128.303 us; speedup vs baseline: 1.0180x; 1.0180x over previous
//
#include <hip/hip_runtime.h>

#define EPS 1e-5f

typedef unsigned short u16;
typedef __attribute__((ext_vector_type(8))) __bf16 bf16x8;
typedef __attribute__((ext_vector_type(4))) float f32x4;
typedef __attribute__((ext_vector_type(8))) unsigned short ushort8;

__device__ inline float bf2f(u16 h) {
  union { unsigned u; float f; } x; x.u = ((unsigned)h) << 16; return x.f;
}
__device__ inline u16 f2bf(float f) {
  union { float f; unsigned u; } x; x.f = f;
  unsigned r = x.u + 0x7fffu + ((x.u >> 16) & 1u);
  return (u16)(r >> 16);
}
__device__ inline float sigmoidf(float x) { return 1.0f / (1.0f + __expf(-x)); }

// ---------------- cast: 4 equal-size f32 -> bf16(u16) arrays ----------------
__global__ __launch_bounds__(256) void cast4_f32_bf16(
    const float* __restrict__ s0, const float* __restrict__ s1,
    const float* __restrict__ s2, const float* __restrict__ s3,
    u16* __restrict__ d0, u16* __restrict__ d1,
    u16* __restrict__ d2, u16* __restrict__ d3, int n)
{
  const float* s = (blockIdx.y == 0) ? s0 : (blockIdx.y == 1) ? s1 : (blockIdx.y == 2) ? s2 : s3;
  u16*         d = (blockIdx.y == 0) ? d0 : (blockIdx.y == 1) ? d1 : (blockIdx.y == 2) ? d2 : d3;
  int i = (blockIdx.x * 256 + threadIdx.x) * 8;
  if (i >= n) return;
  float4 a = *(const float4*)(s + i);
  float4 b = *(const float4*)(s + i + 4);
  ushort8 o;
  o[0] = f2bf(a.x); o[1] = f2bf(a.y); o[2] = f2bf(a.z); o[3] = f2bf(a.w);
  o[4] = f2bf(b.x); o[5] = f2bf(b.y); o[6] = f2bf(b.z); o[7] = f2bf(b.w);
  *(ushort8*)(d + i) = o;
}

// ---------------- GEMM: C[m][n] = sum_k A[m][k] * W[n][k] -------------------
// m201-faithful 8-phase reconstruction. 256x256 tile, BK=64, 512 thr (8 waves,
// 2Mx4N), LDS 128 KiB as K-HALF planes sA/sB[dbuf][kh][256x32] (kh planes give
// race-free staging windows: kh0(t) fully read by ph2 -> ph3/4 may stage
// kh0(t+2) into the same dbuf). Per K-tile, 4 phases = (kh, mi-half):
//   ph1 (kh0, mi0-3): 8 ds_read (A4+B4); stage A-kh1(t+1)
//   ph2 (kh0, mi4-7): 4 ds_read (B reused); stage B-kh1(t+1); vmcnt(6)
//   ph3 (kh1, mi0-3): 8 ds_read;           stage A-kh0(t+2)
//   ph4 (kh1, mi4-7): 4 ds_read;           stage B-kh0(t+2); vmcnt(6)
// Each phase: reads; stage; s_barrier; lgkmcnt(0)+sched_barrier(0) [rule 18];
// setprio(1) 16xMFMA setprio(0); s_barrier. vmcnt waits sit BEFORE the
// ph2/ph4 trailing barriers (wait-then-barrier => collective guarantee).
// T2: 4-slot swizzle slot=k8^(row&3) per plane (balanced: 8 lanes/bank-group
// = minimum, 0 conflicts), staged via pre-swizzled global source + linear
// LDS dest. T1: bijective XCD swizzle. gload_lds offset-imm NEVER used (R6).
#define MFMA_ __builtin_amdgcn_mfma_f32_16x16x32_bf16
#define ASG __attribute__((address_space(1)))
#define ASL __attribute__((address_space(3)))

#define GLL(p, lds) __builtin_amdgcn_global_load_lds( \
    (const ASG void*)(p), (ASL void*)(lds), 16, 0, 0);

#define STG_A(buf, kh, tt) { \
  GLL(gAs + (size_t)(tt) * 64 + (kh) * 32, &sA[buf][kh][tid * 8]) \
  GLL(gAs + (size_t)128 * K + (size_t)(tt) * 64 + (kh) * 32, &sA[buf][kh][(512 + tid) * 8]) }
#define STG_B(buf, kh, tt) { \
  GLL(gBs + (size_t)(tt) * 64 + (kh) * 32, &sB[buf][kh][tid * 8]) \
  GLL(gBs + (size_t)128 * K + (size_t)(tt) * 64 + (kh) * 32, &sB[buf][kh][(512 + tid) * 8]) }

#define LDAf(buf, kh, mi) (*(const bf16x8*)&sA[buf][kh][(arow + (mi) * 16) * 32 + aslot])
#define LDBf(buf, kh, ni) (*(const bf16x8*)&sB[buf][kh][(brow + (ni) * 16) * 32 + bslot])

#define RD_AB(buf, kh, m0) \
  a0 = LDAf(buf, kh, m0 + 0); a1 = LDAf(buf, kh, m0 + 1); \
  a2 = LDAf(buf, kh, m0 + 2); a3 = LDAf(buf, kh, m0 + 3); \
  b0 = LDBf(buf, kh, 0); b1 = LDBf(buf, kh, 1); \
  b2 = LDBf(buf, kh, 2); b3 = LDBf(buf, kh, 3);

#define RD_A(buf, kh, m0) \
  a0 = LDAf(buf, kh, m0 + 0); a1 = LDAf(buf, kh, m0 + 1); \
  a2 = LDAf(buf, kh, m0 + 2); a3 = LDAf(buf, kh, m0 + 3);

#define BAR __builtin_amdgcn_s_barrier();
#define LGKM0 { asm volatile("s_waitcnt lgkmcnt(0)" ::: "memory"); \
                __builtin_amdgcn_sched_barrier(0); }
#define VMW(n) asm volatile("s_waitcnt vmcnt(" #n ")" ::: "memory");

#define PH_MFMA(m0) \
  __builtin_amdgcn_s_setprio(1); \
  acc[m0 + 0][0] = MFMA_(a0, b0, acc[m0 + 0][0], 0, 0, 0); \
  acc[m0 + 0][1] = MFMA_(a0, b1, acc[m0 + 0][1], 0, 0, 0); \
  acc[m0 + 0][2] = MFMA_(a0, b2, acc[m0 + 0][2], 0, 0, 0); \
  acc[m0 + 0][3] = MFMA_(a0, b3, acc[m0 + 0][3], 0, 0, 0); \
  acc[m0 + 1][0] = MFMA_(a1, b0, acc[m0 + 1][0], 0, 0, 0); \
  acc[m0 + 1][1] = MFMA_(a1, b1, acc[m0 + 1][1], 0, 0, 0); \
  acc[m0 + 1][2] = MFMA_(a1, b2, acc[m0 + 1][2], 0, 0, 0); \
  acc[m0 + 1][3] = MFMA_(a1, b3, acc[m0 + 1][3], 0, 0, 0); \
  acc[m0 + 2][0] = MFMA_(a2, b0, acc[m0 + 2][0], 0, 0, 0); \
  acc[m0 + 2][1] = MFMA_(a2, b1, acc[m0 + 2][1], 0, 0, 0); \
  acc[m0 + 2][2] = MFMA_(a2, b2, acc[m0 + 2][2], 0, 0, 0); \
  acc[m0 + 2][3] = MFMA_(a2, b3, acc[m0 + 2][3], 0, 0, 0); \
  acc[m0 + 3][0] = MFMA_(a3, b0, acc[m0 + 3][0], 0, 0, 0); \
  acc[m0 + 3][1] = MFMA_(a3, b1, acc[m0 + 3][1], 0, 0, 0); \
  acc[m0 + 3][2] = MFMA_(a3, b2, acc[m0 + 3][2], 0, 0, 0); \
  acc[m0 + 3][3] = MFMA_(a3, b3, acc[m0 + 3][3], 0, 0, 0); \
  __builtin_amdgcn_s_setprio(0);

__global__ __launch_bounds__(512, 2) void gemm256_dual(
    const u16* __restrict__ A0, const u16* __restrict__ W0, u16* __restrict__ C0,
    const u16* __restrict__ A1, const u16* __restrict__ W1, u16* __restrict__ C1)
{
  constexpr int K = 1024, N = 4096, NT = 16;  // K-tiles of 64

  __shared__ __attribute__((aligned(16))) u16 sA[2][2][256 * 32];  // 64 KiB
  __shared__ __attribute__((aligned(16))) u16 sB[2][2][256 * 32];  // 64 KiB

  // T1: bijective XCD swizzle (512 blocks % 8 XCDs == 0)
  const int b0_ = blockIdx.x;
  const int bid = (b0_ & 7) * 64 + (b0_ >> 3);

  const u16* A  = (bid < 256) ? A0 : A1;
  const u16* Wm = (bid < 256) ? W0 : W1;
  u16*       C  = (bid < 256) ? C0 : C1;
  const int b2 = bid & 255;
  const int bm = (b2 >> 4) << 8;
  const int bn = (b2 & 15) << 8;

  const int tid = threadIdx.x;
  const int l  = tid & 63;
  const int w  = tid >> 6;   // wave 0..7
  const int wr = w >> 2;     // 0..1  -> M offset wr*128
  const int wc = w & 3;      // 0..3  -> N offset wc*64
  (void)w;

  // staging: thread stages chunk c = tid (rows 0-127) and c = 512+tid (rows
  // 128-255) of each 16 KiB plane; LDS linear dest c*16B -> row c>>2, slot c&3.
  // Global source slot pre-swizzled: k8_src = (tid&3) ^ (row&3).
  const int srow  = tid >> 2;                       // 0..127
  const int sslot = (tid & 3) ^ (srow & 3);
  const u16* gAs = A  + (size_t)(bm + srow) * K + sslot * 8;
  const u16* gBs = Wm + (size_t)(bn + srow) * K + sslot * 8;

  // fragment reads: row = base + mi*16 + (l&15), k8-in-plane = l>>4,
  // slot = k8 ^ (row&3) = (l>>4) ^ (l&3)  [bases are multiples of 16]
  const int arow = wr * 128 + (l & 15);
  const int brow = wc * 64 + (l & 15);
  const int aslot = ((l >> 4) ^ (l & 3)) * 8;
  const int bslot = aslot;

  f32x4 acc[8][4];
#pragma unroll
  for (int i = 0; i < 8; ++i)
#pragma unroll
    for (int j = 0; j < 4; ++j) acc[i][j] = (f32x4){0.f, 0.f, 0.f, 0.f};

  // prologue: K0(0), then K1(0), K0(1)  (12 loads; wait oldest 4 -> vmcnt(8))
  STG_A(0, 0, 0) STG_B(0, 0, 0)
  STG_A(0, 1, 0) STG_B(0, 1, 0)
  STG_A(1, 0, 1) STG_B(1, 0, 1)
  VMW(8)
  BAR

  for (int t = 0; t < NT; ++t) {
    const int cur = t & 1, nxt = cur ^ 1;
    bf16x8 a0, a1, a2, a3, b0, b1, b2, b3;

    // ---- ph1: kh0, mi 0-3 ----
    RD_AB(cur, 0, 0)
    if (t < NT - 1) STG_A(nxt, 1, t + 1)
    BAR LGKM0
    PH_MFMA(0)
    BAR

    // ---- ph2: kh0, mi 4-7 ----
    RD_A(cur, 0, 4)
    if (t < NT - 1) STG_B(nxt, 1, t + 1)
    BAR LGKM0
    PH_MFMA(4)
    if (t < NT - 1) { VMW(6) } else { VMW(0) }   // guard kh1(t) reads
    BAR

    // ---- ph3: kh1, mi 0-3 ----
    RD_AB(cur, 1, 0)
    if (t < NT - 2) STG_A(cur, 0, t + 2)
    BAR LGKM0
    PH_MFMA(0)
    BAR

    // ---- ph4: kh1, mi 4-7 ----
    RD_A(cur, 1, 4)
    if (t < NT - 2) STG_B(cur, 0, t + 2)
    BAR LGKM0
    PH_MFMA(4)
    if (t < NT - 2) { VMW(6) }                   // guard kh0(t+1) reads
    else if (t == NT - 2) { VMW(4) }
    BAR
  }

  // C write: col = lane&15, row = (lane>>4)*4 + reg  (m89/m91-verified layout)
  const int ccol = bn + wc * 64 + (l & 15);
  const int crow = bm + wr * 128 + (l >> 4) * 4;
#pragma unroll
  for (int mi = 0; mi < 8; ++mi) {
#pragma unroll
    for (int ni = 0; ni < 4; ++ni) {
      int col = ccol + ni * 16;
#pragma unroll
      for (int r = 0; r < 4; ++r) {
        int row = crow + mi * 16 + r;
        C[(size_t)row * N + col] = f2bf(acc[mi][ni][r]);
      }
    }
  }
}

// ---------------- fused LN(ig) + LN(hg) + gates + cell-LN + outputs ----------
__global__ __launch_bounds__(256) void lstm_epilogue(
    const u16* __restrict__ ig, const u16* __restrict__ hg,
    const float* __restrict__ cx,
    const float* __restrict__ gi, const float* __restrict__ bi,
    const float* __restrict__ gh, const float* __restrict__ bh,
    const float* __restrict__ gc, const float* __restrict__ bc,
    float* __restrict__ out)
{
  const int b = blockIdx.x;
  const int t = threadIdx.x;
  const u16* igr = ig + (size_t)b * 4096;
  const u16* hgr = hg + (size_t)b * 4096;

  __shared__ float redbuf[16];

  float iv[16], hv[16];
  float s_i = 0.f, q_i = 0.f, s_h = 0.f, q_h = 0.f;
#pragma unroll
  for (int i = 0; i < 16; ++i) {
    float a = bf2f(igr[t + 256 * i]);
    float c = bf2f(hgr[t + 256 * i]);
    iv[i] = a; hv[i] = c;
    s_i += a; q_i += a * a; s_h += c; q_h += c * c;
  }
#pragma unroll
  for (int off = 32; off > 0; off >>= 1) {
    s_i += __shfl_xor(s_i, off);
    q_i += __shfl_xor(q_i, off);
    s_h += __shfl_xor(s_h, off);
    q_h += __shfl_xor(q_h, off);
  }
  {
    int wv = t >> 6;
    if ((t & 63) == 0) {
      redbuf[wv] = s_i; redbuf[wv + 4] = q_i;
      redbuf[wv + 8] = s_h; redbuf[wv + 12] = q_h;
    }
    __syncthreads();
    s_i = redbuf[0] + redbuf[1] + redbuf[2] + redbuf[3];
    q_i = redbuf[4] + redbuf[5] + redbuf[6] + redbuf[7];
    s_h = redbuf[8] + redbuf[9] + redbuf[10] + redbuf[11];
    q_h = redbuf[12] + redbuf[13] + redbuf[14] + redbuf[15];
    __syncthreads();
  }
  const float inv4096 = 1.0f / 4096.0f;
  float mu_i = s_i * inv4096;
  float rs_i = rsqrtf(q_i * inv4096 - mu_i * mu_i + EPS);
  float mu_h = s_h * inv4096;
  float rs_h = rsqrtf(q_h * inv4096 - mu_h * mu_h + EPS);

  float c_pre[4], og[4];
  float s_c = 0.f, q_c = 0.f;
#pragma unroll
  for (int i = 0; i < 4; ++i) {
    int h = t + 256 * i;
    float g_in = ((iv[i]      - mu_i) * rs_i * gi[h]        + bi[h]) +
                 ((hv[i]      - mu_h) * rs_h * gh[h]        + bh[h]);
    float g_fg = ((iv[i + 4]  - mu_i) * rs_i * gi[h + 1024] + bi[h + 1024]) +
                 ((hv[i + 4]  - mu_h) * rs_h * gh[h + 1024] + bh[h + 1024]);
    float g_cl = ((iv[i + 8]  - mu_i) * rs_i * gi[h + 2048] + bi[h + 2048]) +
                 ((hv[i + 8]  - mu_h) * rs_h * gh[h + 2048] + bh[h + 2048]);
    float g_og = ((iv[i + 12] - mu_i) * rs_i * gi[h + 3072] + bi[h + 3072]) +
                 ((hv[i + 12] - mu_h) * rs_h * gh[h + 3072] + bh[h + 3072]);
    float in_s = sigmoidf(g_in);
    float fg_s = sigmoidf(g_fg);
    float cl_t = tanhf(g_cl);
    og[i] = sigmoidf(g_og);
    c_pre[i] = fg_s * cx[(size_t)b * 1024 + h] + in_s * cl_t;
    s_c += c_pre[i]; q_c += c_pre[i] * c_pre[i];
  }
#pragma unroll
  for (int off = 32; off > 0; off >>= 1) {
    s_c += __shfl_xor(s_c, off);
    q_c += __shfl_xor(q_c, off);
  }
  {
    int wv = t >> 6;
    if ((t & 63) == 0) { redbuf[wv] = s_c; redbuf[wv + 4] = q_c; }
    __syncthreads();
    s_c = redbuf[0] + redbuf[1] + redbuf[2] + redbuf[3];
    q_c = redbuf[4] + redbuf[5] + redbuf[6] + redbuf[7];
  }
  const float inv1024 = 1.0f / 1024.0f;
  float mu_c = s_c * inv1024;
  float rs_c = rsqrtf(q_c * inv1024 - mu_c * mu_c + EPS);

  const size_t BH = (size_t)4096 * 1024;
#pragma unroll
  for (int i = 0; i < 4; ++i) {
    int h = t + 256 * i;
    float cy = (c_pre[i] - mu_c) * rs_c * gc[h] + bc[h];
    float hy = og[i] * tanhf(cy);
    size_t o = (size_t)b * 1024 + h;
    out[o] = hy;
    out[BH + o] = hy;
    out[2 * BH + o] = cy;
  }
}

extern "C" void kernel_launch(void* const* d_in, const int* in_sizes, int n_in,
                              void* d_out, int out_size, void* d_ws, size_t ws_size,
                              hipStream_t stream) {
  const float* input = (const float*)d_in[0];
  const float* hx    = (const float*)d_in[1];
  const float* cx    = (const float*)d_in[2];
  const float* wih   = (const float*)d_in[3];
  const float* whh   = (const float*)d_in[4];
  const float* gi    = (const float*)d_in[5];
  const float* bi    = (const float*)d_in[6];
  const float* gh    = (const float*)d_in[7];
  const float* bh    = (const float*)d_in[8];
  const float* gc    = (const float*)d_in[9];
  const float* bc    = (const float*)d_in[10];
  float* out = (float*)d_out;

  char* wsp = (char*)d_ws;
  u16* a_bf  = (u16*)(wsp);
  u16* h_bf  = (u16*)(wsp + ((size_t)8  << 20));
  u16* wi_bf = (u16*)(wsp + ((size_t)16 << 20));
  u16* wh_bf = (u16*)(wsp + ((size_t)24 << 20));
  u16* ig_bf = (u16*)(wsp + ((size_t)32 << 20));
  u16* hg_bf = (u16*)(wsp + ((size_t)64 << 20));

  const int nper = 4096 * 1024;
  dim3 cgrid(nper / 8 / 256, 4);
  cast4_f32_bf16<<<cgrid, 256, 0, stream>>>(input, hx, wih, whh,
                                            a_bf, h_bf, wi_bf, wh_bf, nper);

  gemm256_dual<<<512, 512, 0, stream>>>(a_bf, wi_bf, ig_bf,
                                        h_bf, wh_bf, hg_bf);

  lstm_epilogue<<<4096, 256, 0, stream>>>(ig_bf, hg_bf, cx,
                                          gi, bi, gh, bh, gc, bc, out);
}

// Round 9
// 124.395 us; speedup vs baseline: 1.0500x; 1.0314x over previous
//
#include <hip/hip_runtime.h>

#define EPS 1e-5f

typedef unsigned short u16;
typedef __attribute__((ext_vector_type(8))) __bf16 bf16x8;
typedef __attribute__((ext_vector_type(4))) float f32x4;
typedef __attribute__((ext_vector_type(8))) unsigned short ushort8;

__device__ inline float bf2f(u16 h) {
  union { unsigned u; float f; } x; x.u = ((unsigned)h) << 16; return x.f;
}
__device__ inline u16 f2bf(float f) {
  union { float f; unsigned u; } x; x.f = f;
  unsigned r = x.u + 0x7fffu + ((x.u >> 16) & 1u);
  return (u16)(r >> 16);
}
__device__ inline float sigmoidf(float x) { return 1.0f / (1.0f + __expf(-x)); }

// ---------------- cast: 4 equal-size f32 -> bf16(u16) arrays ----------------
__global__ __launch_bounds__(256) void cast4_f32_bf16(
    const float* __restrict__ s0, const float* __restrict__ s1,
    const float* __restrict__ s2, const float* __restrict__ s3,
    u16* __restrict__ d0, u16* __restrict__ d1,
    u16* __restrict__ d2, u16* __restrict__ d3, int n)
{
  const float* s = (blockIdx.y == 0) ? s0 : (blockIdx.y == 1) ? s1 : (blockIdx.y == 2) ? s2 : s3;
  u16*         d = (blockIdx.y == 0) ? d0 : (blockIdx.y == 1) ? d1 : (blockIdx.y == 2) ? d2 : d3;
  int i = (blockIdx.x * 256 + threadIdx.x) * 8;
  if (i >= n) return;
  float4 a = *(const float4*)(s + i);
  float4 b = *(const float4*)(s + i + 4);
  ushort8 o;
  o[0] = f2bf(a.x); o[1] = f2bf(a.y); o[2] = f2bf(a.z); o[3] = f2bf(a.w);
  o[4] = f2bf(b.x); o[5] = f2bf(b.y); o[6] = f2bf(b.z); o[7] = f2bf(b.w);
  *(ushort8*)(d + i) = o;
}

// ---------------- GEMM: C[m][n] = sum_k A[m][k] * W[n][k] -------------------
// MINIMUM-SYNC tile (R9). 256x256, BK=64, 512 thr (8 waves 2Mx4N), 128 KiB
// LDS dbuf, R5-verified swizzle (0 conflicts). Per K-tile only TWO barriers:
//   STAGE(t+1); vmcnt(8); BAR_B;  [24 ds_read + 64 MFMA, NO internal sync --
//   compiler emits counted lgkmcnt];  BAR_A
// Race proof: BAR_A(t-1) => all waves' reads of buf[nxt] retired (reads
// precede MFMA via lgkm, MFMA precedes BAR_A) before anyone stages into it.
// VMW-before-BAR_B => per-wave vmcnt is collective. Between BAR_B and BAR_A:
// ~4300 cyc of unsynchronized drift -> wave A's ds_reads overlap wave B's
// MFMAs (the cross-wave LDS||MFMA overlap R3/R5/R8's lockstep prevented).
// T1 XCD swizzle; staging by pointer-advance only (R6 lesson).
#define MFMA_ __builtin_amdgcn_mfma_f32_16x16x32_bf16
#define ASG __attribute__((address_space(1)))
#define ASL __attribute__((address_space(3)))

#define GLL(p, lds) __builtin_amdgcn_global_load_lds( \
    (const ASG void*)(p), (ASL void*)(lds), 16, 0, 0);

#define STAGE_A(nx, kn) \
  GLL(gA_0 + (kn), &sA[nx][((w << 6)       ) * 8]) \
  GLL(gA_1 + (kn), &sA[nx][((w << 6) +  512) * 8]) \
  GLL(gA_2 + (kn), &sA[nx][((w << 6) + 1024) * 8]) \
  GLL(gA_3 + (kn), &sA[nx][((w << 6) + 1536) * 8])
#define STAGE_B(nx, kn) \
  GLL(gB_0 + (kn), &sB[nx][((w << 6)       ) * 8]) \
  GLL(gB_1 + (kn), &sB[nx][((w << 6) +  512) * 8]) \
  GLL(gB_2 + (kn), &sB[nx][((w << 6) + 1024) * 8]) \
  GLL(gB_3 + (kn), &sB[nx][((w << 6) + 1536) * 8])

#define LDA(mi, sl) (*(const bf16x8*)&sa[(arow + (mi) * 16) * 64 + (sl)])
#define LDB(ni, sl) (*(const bf16x8*)&sb[(brow + (ni) * 16) * 64 + (sl)])

#define VMW(n) asm volatile("s_waitcnt vmcnt(" #n ")" ::: "memory");
#define BAR __builtin_amdgcn_s_barrier();

// 32 MFMA: mi 0-7 x ni 0-3 at one K-half (frags a0..a7, b0..b3)
#define MFMA32 \
  __builtin_amdgcn_s_setprio(1); \
  acc[0][0] = MFMA_(a0, b0, acc[0][0], 0, 0, 0); \
  acc[0][1] = MFMA_(a0, b1, acc[0][1], 0, 0, 0); \
  acc[0][2] = MFMA_(a0, b2, acc[0][2], 0, 0, 0); \
  acc[0][3] = MFMA_(a0, b3, acc[0][3], 0, 0, 0); \
  acc[1][0] = MFMA_(a1, b0, acc[1][0], 0, 0, 0); \
  acc[1][1] = MFMA_(a1, b1, acc[1][1], 0, 0, 0); \
  acc[1][2] = MFMA_(a1, b2, acc[1][2], 0, 0, 0); \
  acc[1][3] = MFMA_(a1, b3, acc[1][3], 0, 0, 0); \
  acc[2][0] = MFMA_(a2, b0, acc[2][0], 0, 0, 0); \
  acc[2][1] = MFMA_(a2, b1, acc[2][1], 0, 0, 0); \
  acc[2][2] = MFMA_(a2, b2, acc[2][2], 0, 0, 0); \
  acc[2][3] = MFMA_(a2, b3, acc[2][3], 0, 0, 0); \
  acc[3][0] = MFMA_(a3, b0, acc[3][0], 0, 0, 0); \
  acc[3][1] = MFMA_(a3, b1, acc[3][1], 0, 0, 0); \
  acc[3][2] = MFMA_(a3, b2, acc[3][2], 0, 0, 0); \
  acc[3][3] = MFMA_(a3, b3, acc[3][3], 0, 0, 0); \
  acc[4][0] = MFMA_(a4, b0, acc[4][0], 0, 0, 0); \
  acc[4][1] = MFMA_(a4, b1, acc[4][1], 0, 0, 0); \
  acc[4][2] = MFMA_(a4, b2, acc[4][2], 0, 0, 0); \
  acc[4][3] = MFMA_(a4, b3, acc[4][3], 0, 0, 0); \
  acc[5][0] = MFMA_(a5, b0, acc[5][0], 0, 0, 0); \
  acc[5][1] = MFMA_(a5, b1, acc[5][1], 0, 0, 0); \
  acc[5][2] = MFMA_(a5, b2, acc[5][2], 0, 0, 0); \
  acc[5][3] = MFMA_(a5, b3, acc[5][3], 0, 0, 0); \
  acc[6][0] = MFMA_(a6, b0, acc[6][0], 0, 0, 0); \
  acc[6][1] = MFMA_(a6, b1, acc[6][1], 0, 0, 0); \
  acc[6][2] = MFMA_(a6, b2, acc[6][2], 0, 0, 0); \
  acc[6][3] = MFMA_(a6, b3, acc[6][3], 0, 0, 0); \
  acc[7][0] = MFMA_(a7, b0, acc[7][0], 0, 0, 0); \
  acc[7][1] = MFMA_(a7, b1, acc[7][1], 0, 0, 0); \
  acc[7][2] = MFMA_(a7, b2, acc[7][2], 0, 0, 0); \
  acc[7][3] = MFMA_(a7, b3, acc[7][3], 0, 0, 0); \
  __builtin_amdgcn_s_setprio(0);

#define RD12(sl) \
  b0 = LDB(0, sl); b1 = LDB(1, sl); b2 = LDB(2, sl); b3 = LDB(3, sl); \
  a0 = LDA(0, sl); a1 = LDA(1, sl); a2 = LDA(2, sl); a3 = LDA(3, sl); \
  a4 = LDA(4, sl); a5 = LDA(5, sl); a6 = LDA(6, sl); a7 = LDA(7, sl);

__global__ __launch_bounds__(512, 2) void gemm256_dual(
    const u16* __restrict__ A0, const u16* __restrict__ W0, u16* __restrict__ C0,
    const u16* __restrict__ A1, const u16* __restrict__ W1, u16* __restrict__ C1)
{
  constexpr int K = 1024, N = 4096, NT = 16;  // K-tiles of 64

  __shared__ __attribute__((aligned(16))) u16 sA[2][256 * 64];  // 2 x 32 KiB
  __shared__ __attribute__((aligned(16))) u16 sB[2][256 * 64];  // 2 x 32 KiB

  // T1: bijective XCD swizzle (512 blocks % 8 XCDs == 0)
  const int b0_ = blockIdx.x;
  const int bid = (b0_ & 7) * 64 + (b0_ >> 3);

  const u16* A  = (bid < 256) ? A0 : A1;
  const u16* Wm = (bid < 256) ? W0 : W1;
  u16*       C  = (bid < 256) ? C0 : C1;
  const int b2 = bid & 255;
  const int bm = (b2 >> 4) << 8;
  const int bn = (b2 & 15) << 8;

  const int tid = threadIdx.x;
  const int l  = tid & 63;
  const int w  = tid >> 6;   // wave 0..7
  const int wr = w >> 2;     // 0..1  -> M offset wr*128
  const int wc = w & 3;      // 0..3  -> N offset wc*64

  // staging (R5-verified): thread tid, chunk i -> LDS row i*64 + (tid>>3),
  // slot tid&7 linear; global source column pre-swizzled k8 = (tid&7)^(row&7)
  const int rb   = tid >> 3;
  const int slot = (tid & 7) ^ (rb & 7);
  const u16* gA_0 = A  + (size_t)(bm + rb) * K + slot * 8;
  const u16* gA_1 = gA_0 + (size_t)64  * K;
  const u16* gA_2 = gA_0 + (size_t)128 * K;
  const u16* gA_3 = gA_0 + (size_t)192 * K;
  const u16* gB_0 = Wm + (size_t)(bn + rb) * K + slot * 8;
  const u16* gB_1 = gB_0 + (size_t)64  * K;
  const u16* gB_2 = gB_0 + (size_t)128 * K;
  const u16* gB_3 = gB_0 + (size_t)192 * K;

  // fragment reads (R5-verified): elem = row*64 + ((k8 ^ (row&7))*8)
  const int arow = wr * 128 + (l & 15);
  const int brow = wc * 64 + (l & 15);
  const int sl0 = (((l >> 4) + 0) ^ (l & 7)) * 8;  // K 0-31
  const int sl1 = (((l >> 4) + 4) ^ (l & 7)) * 8;  // K 32-63

  f32x4 acc[8][4];
#pragma unroll
  for (int i = 0; i < 8; ++i)
#pragma unroll
    for (int j = 0; j < 4; ++j) acc[i][j] = (f32x4){0.f, 0.f, 0.f, 0.f};

  // prologue: stage K-tile 0 into buffer 0 (8 loads in flight, no drain)
  STAGE_A(0, 0)
  STAGE_B(0, 0)

  for (int t = 0; t < NT; ++t) {
    const int cur = t & 1, nxt = cur ^ 1;
    const u16* sa = sA[cur];
    const u16* sb = sB[cur];

    // stage t+1 (safe: BAR_A(t-1) retired all reads of buf[nxt]);
    // VMW before BAR_B makes tile t's arrival collective.
    if (t < NT - 1) {
      const int kn = (t + 1) << 6;
      STAGE_A(nxt, kn)
      STAGE_B(nxt, kn)
      VMW(8)
    } else {
      VMW(0)
    }
    BAR  // BAR_B

    bf16x8 a0, a1, a2, a3, a4, a5, a6, a7, b0, b1, b2, b3;
    // K-half 0: 12 ds_read_b128 + 32 MFMA (compiler emits counted lgkmcnt)
    RD12(sl0)
    MFMA32
    // K-half 1
    RD12(sl1)
    MFMA32

    BAR  // BAR_A: all this wave's reads retired (lgkm before MFMA) for all
  }

  // C write: col = lane&15, row = (lane>>4)*4 + reg  (m89/m91-verified layout)
  const int ccol = bn + wc * 64 + (l & 15);
  const int crow = bm + wr * 128 + (l >> 4) * 4;
#pragma unroll
  for (int mi = 0; mi < 8; ++mi) {
#pragma unroll
    for (int ni = 0; ni < 4; ++ni) {
      int col = ccol + ni * 16;
#pragma unroll
      for (int r = 0; r < 4; ++r) {
        int row = crow + mi * 16 + r;
        C[(size_t)row * N + col] = f2bf(acc[mi][ni][r]);
      }
    }
  }
}

// ---------------- fused LN(ig) + LN(hg) + gates + cell-LN + outputs ----------
__global__ __launch_bounds__(256) void lstm_epilogue(
    const u16* __restrict__ ig, const u16* __restrict__ hg,
    const float* __restrict__ cx,
    const float* __restrict__ gi, const float* __restrict__ bi,
    const float* __restrict__ gh, const float* __restrict__ bh,
    const float* __restrict__ gc, const float* __restrict__ bc,
    float* __restrict__ out)
{
  const int b = blockIdx.x;
  const int t = threadIdx.x;
  const u16* igr = ig + (size_t)b * 4096;
  const u16* hgr = hg + (size_t)b * 4096;

  __shared__ float redbuf[16];

  float iv[16], hv[16];
  float s_i = 0.f, q_i = 0.f, s_h = 0.f, q_h = 0.f;
#pragma unroll
  for (int i = 0; i < 16; ++i) {
    float a = bf2f(igr[t + 256 * i]);
    float c = bf2f(hgr[t + 256 * i]);
    iv[i] = a; hv[i] = c;
    s_i += a; q_i += a * a; s_h += c; q_h += c * c;
  }
#pragma unroll
  for (int off = 32; off > 0; off >>= 1) {
    s_i += __shfl_xor(s_i, off);
    q_i += __shfl_xor(q_i, off);
    s_h += __shfl_xor(s_h, off);
    q_h += __shfl_xor(q_h, off);
  }
  {
    int wv = t >> 6;
    if ((t & 63) == 0) {
      redbuf[wv] = s_i; redbuf[wv + 4] = q_i;
      redbuf[wv + 8] = s_h; redbuf[wv + 12] = q_h;
    }
    __syncthreads();
    s_i = redbuf[0] + redbuf[1] + redbuf[2] + redbuf[3];
    q_i = redbuf[4] + redbuf[5] + redbuf[6] + redbuf[7];
    s_h = redbuf[8] + redbuf[9] + redbuf[10] + redbuf[11];
    q_h = redbuf[12] + redbuf[13] + redbuf[14] + redbuf[15];
    __syncthreads();
  }
  const float inv4096 = 1.0f / 4096.0f;
  float mu_i = s_i * inv4096;
  float rs_i = rsqrtf(q_i * inv4096 - mu_i * mu_i + EPS);
  float mu_h = s_h * inv4096;
  float rs_h = rsqrtf(q_h * inv4096 - mu_h * mu_h + EPS);

  float c_pre[4], og[4];
  float s_c = 0.f, q_c = 0.f;
#pragma unroll
  for (int i = 0; i < 4; ++i) {
    int h = t + 256 * i;
    float g_in = ((iv[i]      - mu_i) * rs_i * gi[h]        + bi[h]) +
                 ((hv[i]      - mu_h) * rs_h * gh[h]        + bh[h]);
    float g_fg = ((iv[i + 4]  - mu_i) * rs_i * gi[h + 1024] + bi[h + 1024]) +
                 ((hv[i + 4]  - mu_h) * rs_h * gh[h + 1024] + bh[h + 1024]);
    float g_cl = ((iv[i + 8]  - mu_i) * rs_i * gi[h + 2048] + bi[h + 2048]) +
                 ((hv[i + 8]  - mu_h) * rs_h * gh[h + 2048] + bh[h + 2048]);
    float g_og = ((iv[i + 12] - mu_i) * rs_i * gi[h + 3072] + bi[h + 3072]) +
                 ((hv[i + 12] - mu_h) * rs_h * gh[h + 3072] + bh[h + 3072]);
    float in_s = sigmoidf(g_in);
    float fg_s = sigmoidf(g_fg);
    float cl_t = tanhf(g_cl);
    og[i] = sigmoidf(g_og);
    c_pre[i] = fg_s * cx[(size_t)b * 1024 + h] + in_s * cl_t;
    s_c += c_pre[i]; q_c += c_pre[i] * c_pre[i];
  }
#pragma unroll
  for (int off = 32; off > 0; off >>= 1) {
    s_c += __shfl_xor(s_c, off);
    q_c += __shfl_xor(q_c, off);
  }
  {
    int wv = t >> 6;
    if ((t & 63) == 0) { redbuf[wv] = s_c; redbuf[wv + 4] = q_c; }
    __syncthreads();
    s_c = redbuf[0] + redbuf[1] + redbuf[2] + redbuf[3];
    q_c = redbuf[4] + redbuf[5] + redbuf[6] + redbuf[7];
  }
  const float inv1024 = 1.0f / 1024.0f;
  float mu_c = s_c * inv1024;
  float rs_c = rsqrtf(q_c * inv1024 - mu_c * mu_c + EPS);

  const size_t BH = (size_t)4096 * 1024;
#pragma unroll
  for (int i = 0; i < 4; ++i) {
    int h = t + 256 * i;
    float cy = (c_pre[i] - mu_c) * rs_c * gc[h] + bc[h];
    float hy = og[i] * tanhf(cy);
    size_t o = (size_t)b * 1024 + h;
    out[o] = hy;
    out[BH + o] = hy;
    out[2 * BH + o] = cy;
  }
}

extern "C" void kernel_launch(void* const* d_in, const int* in_sizes, int n_in,
                              void* d_out, int out_size, void* d_ws, size_t ws_size,
                              hipStream_t stream) {
  const float* input = (const float*)d_in[0];
  const float* hx    = (const float*)d_in[1];
  const float* cx    = (const float*)d_in[2];
  const float* wih   = (const float*)d_in[3];
  const float* whh   = (const float*)d_in[4];
  const float* gi    = (const float*)d_in[5];
  const float* bi    = (const float*)d_in[6];
  const float* gh    = (const float*)d_in[7];
  const float* bh    = (const float*)d_in[8];
  const float* gc    = (const float*)d_in[9];
  const float* bc    = (const float*)d_in[10];
  float* out = (float*)d_out;

  char* wsp = (char*)d_ws;
  u16* a_bf  = (u16*)(wsp);
  u16* h_bf  = (u16*)(wsp + ((size_t)8  << 20));
  u16* wi_bf = (u16*)(wsp + ((size_t)16 << 20));
  u16* wh_bf = (u16*)(wsp + ((size_t)24 << 20));
  u16* ig_bf = (u16*)(wsp + ((size_t)32 << 20));
  u16* hg_bf = (u16*)(wsp + ((size_t)64 << 20));

  const int nper = 4096 * 1024;
  dim3 cgrid(nper / 8 / 256, 4);
  cast4_f32_bf16<<<cgrid, 256, 0, stream>>>(input, hx, wih, whh,
                                            a_bf, h_bf, wi_bf, wh_bf, nper);

  gemm256_dual<<<512, 512, 0, stream>>>(a_bf, wi_bf, ig_bf,
                                        h_bf, wh_bf, hg_bf);

  lstm_epilogue<<<4096, 256, 0, stream>>>(ig_bf, hg_bf, cx,
                                          gi, bi, gh, bh, gc, bc, out);
}